// Round 7
// baseline (263.381 us; speedup 1.0000x reference)
//
#include <hip/hip_runtime.h>

#define HDIM 256
#define TDIM 256
#define VOUT 10
#define BC   4     // batch rows per block -> 512 blocks = 2 independent blocks/CU

typedef _Float16 f16x8 __attribute__((ext_vector_type(8)));
typedef float    f32x4 __attribute__((ext_vector_type(4)));

__device__ __forceinline__ float fast_tanh(float a) {
    // tanh(a) = 1 - 2/(exp(2a)+1). |a| bounded (~32) -> no clamp needed.
    float e = __expf(2.0f * a);
    return 1.0f - 2.0f * __builtin_amdgcn_rcpf(e + 1.0f);
}

// select v[al] with static indices (no scratch; cndmask chain)
__device__ __forceinline__ float sel4(f32x4 v, int al) {
    float r = v[0];
    r = (al == 1) ? v[1] : r;
    r = (al == 2) ? v[2] : r;
    r = (al == 3) ? v[3] : r;
    return r;
}

// Swapped-operand MFMA recurrence, BC=4, 2 blocks/CU (de-correlated barriers).
// Per step D = Wh^T (256x256) x v^T (256x4). MFMA N=16 slots: lanes alias batch
// row rn=n&3 (4x), alias id al=n>>2 dedups the rg dimension (lane takes rg=al).
// Wave w (0..3) owns h-cols [64w,64w+64) = 4 M-tiles; wfrag in 128 VGPRs.
// v LDS: 16B chunk (c=hcol>>3, rn): addr = c*64+rn*16+(hcol&7)*2 (conflict-free).
// inp planes: f32, chunk-major c*32+rn*8+(hcol&7); rolling 4-plane, filled t+3
// ahead cooperatively (256 thr x 4 unique) in the MFMA shadow.
__global__ __launch_bounds__(256, 2) void rnn_fwd_v7(
    const float* __restrict__ x,    // [B, T]
    const float* __restrict__ We,   // [H]
    const float* __restrict__ be,   // [H]
    const float* __restrict__ Wh,   // [H, H] (in, out)
    const float* __restrict__ bh,   // [H]
    const float* __restrict__ Wo,   // [H, V]
    const float* __restrict__ bo,   // [V]
    float* __restrict__ out)        // [B, V]
{
    __shared__ __align__(16) char  vraw[2][BC * HDIM * 2];   // 2 x 2 KB f16
    __shared__ __align__(16) float inp_lds[4][BC * HDIM];    // 4 x 4 KB f32
    __shared__ float x_lds[BC][TDIM + 2];                    // 4.1 KB
    __shared__ float h_fin[BC][HDIM + 1];                    // 4.1 KB

    const int tid = threadIdx.x;
    const int l   = tid & 63;
    const int w   = tid >> 6;       // wave 0..3 -> h-cols [64w, 64w+64)
    const int n   = l & 15;         // MFMA N slot
    const int rn  = n & 3;          // batch row
    const int al  = n >> 2;         // alias id -> owns rg = al
    const int g   = l >> 4;
    const int u   = 4 * g + al;     // 0..15: hcol low bits
    const int o   = u & 7;
    const int r0  = blockIdx.x * BC;

    // ---- stage x (coalesced) ----
    for (int k = tid; k < BC * TDIM; k += 256) {
        int r = k >> 8, t = k & 255;
        x_lds[r][t] = x[(r0 + r) * TDIM + t];
    }

    // ---- W_h -> register fragments (4 M-tiles = 128 VGPR) ----
    // wfrag[mt][kt][e] = Wh[(kt*32+g*8+e)*H + 64w+16mt+n]
    f16x8 wfrag[4][8];
    #pragma unroll
    for (int mt = 0; mt < 4; ++mt) {
        const int col = 64 * w + 16 * mt + n;
        #pragma unroll
        for (int kt = 0; kt < 8; ++kt) {
            #pragma unroll
            for (int e = 0; e < 8; ++e)
                wfrag[mt][kt][e] = (_Float16)Wh[(kt * 32 + g * 8 + e) * HDIM + col];
        }
    }

    // bh for acc init (all rg; MFMA computes all slots)
    float bhf[4][4];
    #pragma unroll
    for (int mt = 0; mt < 4; ++mt)
        #pragma unroll
        for (int rg = 0; rg < 4; ++rg)
            bhf[mt][rg] = bh[64 * w + 16 * mt + 4 * g + rg];

    // ---- burst (inp-plane) assignment: 256 thr x 4 f32 = 1024/plane ----
    const int c_b  = tid >> 3;          // chunk 0..31
    const int rn_b = (tid >> 1) & 3;
    const int hf_b = tid & 1;
    float Web[4], beb[4];
    #pragma unroll
    for (int r = 0; r < 4; ++r) {
        Web[r] = We[c_b * 8 + hf_b * 4 + r];
        beb[r] = be[c_b * 8 + hf_b * 4 + r];
    }
    const int bidx = c_b * 32 + rn_b * 8 + hf_b * 4;   // f32 index in plane

    // ---- per-mt addresses ----
    int addr_w[4], iidx[4];
    #pragma unroll
    for (int mt = 0; mt < 4; ++mt) {
        const int c = 8 * w + 2 * mt + (u >> 3);       // chunk of owned hcol
        addr_w[mt] = c * 64 + rn * 16 + o * 2;         // f16 byte addr
        iidx[mt]   = c * 32 + rn * 8 + o;              // f32 index
    }
    const int base_r = g * 64 + rn * 16;               // bfrag: + kt*256

    __syncthreads();

    // ---- prologue: inp planes tq = 0,1,2 ----
    #pragma unroll
    for (int tq = 0; tq < 3; ++tq) {
        const float xv = x_lds[rn_b][tq];
        f32x4 pk;
        #pragma unroll
        for (int r = 0; r < 4; ++r)
            pk[r] = fast_tanh(xv * Web[r] + beb[r]);
        *(f32x4*)&inp_lds[tq][bidx] = pk;
    }
    __syncthreads();

    // ---- v(0) = inp(0) (f32 -> f16 copy) ----
    #pragma unroll
    for (int mt = 0; mt < 4; ++mt)
        *(_Float16*)(&vraw[0][0] + addr_w[mt]) = (_Float16)inp_lds[0][iidx[mt]];
    __syncthreads();

    int cur = 0;
    #pragma unroll 1
    for (int t = 0; t < TDIM; ++t) {
        const char* vr = &vraw[cur][0];
        const bool last = (t + 1 == TDIM);

        // B-frags: per 16-lane phase 4 unique 16B lines of one chunk (broadcast)
        f16x8 bfrag[8];
        #pragma unroll
        for (int kt = 0; kt < 8; ++kt)
            bfrag[kt] = *(const f16x8*)(vr + base_r + kt * 256);

        // inp(t+1) for this step's v-write (1 f32 per mt)
        float ip[4];
        {
            const float* ipl = &inp_lds[(t + 1) & 3][0];
            #pragma unroll
            for (int mt = 0; mt < 4; ++mt)
                ip[mt] = ipl[iidx[mt]];
        }

        // shadow: cooperative inp plane t+3 (unique work, hides in lgkm/MFMA wait)
        {
            const int tq = t + 3;
            if (tq < TDIM) {
                const float xv = x_lds[rn_b][tq];
                f32x4 pk;
                #pragma unroll
                for (int r = 0; r < 4; ++r)
                    pk[r] = fast_tanh(xv * Web[r] + beb[r]);
                *(f32x4*)&inp_lds[tq & 3][bidx] = pk;
            }
        }

        // 8 independent MFMA chains (mt x kt-parity), 4-deep
        f32x4 accE[4], accO[4];
        #pragma unroll
        for (int mt = 0; mt < 4; ++mt) {
            accE[mt][0] = bhf[mt][0]; accE[mt][1] = bhf[mt][1];
            accE[mt][2] = bhf[mt][2]; accE[mt][3] = bhf[mt][3];
            accO[mt][0] = 0.0f; accO[mt][1] = 0.0f;
            accO[mt][2] = 0.0f; accO[mt][3] = 0.0f;
        }
        #pragma unroll
        for (int kp = 0; kp < 4; ++kp) {
            #pragma unroll
            for (int mt = 0; mt < 4; ++mt)
                accE[mt] = __builtin_amdgcn_mfma_f32_16x16x32_f16(
                    wfrag[mt][2 * kp], bfrag[2 * kp], accE[mt], 0, 0, 0);
            #pragma unroll
            for (int mt = 0; mt < 4; ++mt)
                accO[mt] = __builtin_amdgcn_mfma_f32_16x16x32_f16(
                    wfrag[mt][2 * kp + 1], bfrag[2 * kp + 1], accO[mt], 0, 0, 0);
        }

        // 4-way dedup'd tail: lane handles rg = al only (1 tanh per mt)
        if (!last) {
            char* vw = &vraw[cur ^ 1][0];
            #pragma unroll
            for (int mt = 0; mt < 4; ++mt) {
                const float a = sel4(accE[mt], al) + sel4(accO[mt], al);
                const float s = fast_tanh(a) + ip[mt];
                *(_Float16*)(vw + addr_w[mt]) = (_Float16)s;
            }
        } else {
            #pragma unroll
            for (int mt = 0; mt < 4; ++mt) {
                const float a = sel4(accE[mt], al) + sel4(accO[mt], al);
                h_fin[rn][64 * w + 16 * mt + 4 * g + al] = fast_tanh(a);
            }
        }
        cur ^= 1;
        __syncthreads();
    }

    // ---- epilogue: out[r][v] = bo[v] + sum_i h[r][i] * Wo[i*V+v] ----
    if (tid < BC * VOUT) {
        const int r = tid / VOUT, vc = tid - r * VOUT;
        float sacc = bo[vc];
        #pragma unroll 8
        for (int i = 0; i < HDIM; ++i)
            sacc = fmaf(h_fin[r][i], Wo[i * VOUT + vc], sacc);
        out[(r0 + r) * VOUT + vc] = sacc;
    }
}

extern "C" void kernel_launch(void* const* d_in, const int* in_sizes, int n_in,
                              void* d_out, int out_size, void* d_ws, size_t ws_size,
                              hipStream_t stream) {
    const float* x  = (const float*)d_in[0];
    const float* We = (const float*)d_in[1];
    const float* be = (const float*)d_in[2];
    const float* Wh = (const float*)d_in[3];
    const float* bh = (const float*)d_in[4];
    const float* Wo = (const float*)d_in[5];
    const float* bo = (const float*)d_in[6];
    float* out = (float*)d_out;

    const int B = in_sizes[0] / TDIM;      // 2048
    const int nblocks = B / BC;            // 512 -> 2 blocks per CU

    rnn_fwd_v7<<<nblocks, 256, 0, stream>>>(x, We, be, Wh, bh, Wo, bo, out);
}

// Round 8
// 189.538 us; speedup vs baseline: 1.3896x; 1.3896x over previous
//
#include <hip/hip_runtime.h>

#define HDIM 256
#define TDIM 256
#define VOUT 10
#define BC   8     // batch rows per block -> 256 blocks, every CU busy

typedef _Float16 f16x8 __attribute__((ext_vector_type(8)));
typedef float    f32x4 __attribute__((ext_vector_type(4)));

__device__ __forceinline__ float fast_tanh(float a) {
    // tanh(a) = 1 - 2/(exp(2a)+1). |a| bounded (~32) -> no clamp needed.
    float e = __expf(2.0f * a);
    return 1.0f - 2.0f * __builtin_amdgcn_rcpf(e + 1.0f);
}

// v8 = v6 structure (BC=8, 8 waves, 2x N-alias, dedup'd tanh, conflict-free
// chunk-major LDS) + scheduling: setprio around MFMA clusters, shadow-tanh
// moved into the MFMA latency window, ip prefetch at top, last step peeled.
__global__ __launch_bounds__(512, 2) void rnn_fwd_v8(
    const float* __restrict__ x,    // [B, T]
    const float* __restrict__ We,   // [H]
    const float* __restrict__ be,   // [H]
    const float* __restrict__ Wh,   // [H, H] (in, out)
    const float* __restrict__ bh,   // [H]
    const float* __restrict__ Wo,   // [H, V]
    const float* __restrict__ bo,   // [V]
    float* __restrict__ out)        // [B, V]
{
    __shared__ __align__(16) char  vraw[2][BC * HDIM * 2];   // 2 x 4 KB f16
    __shared__ __align__(16) float inp_lds[4][BC * HDIM];    // 4 x 8 KB f32
    __shared__ float x_lds[BC][TDIM + 2];
    __shared__ float h_fin[BC][HDIM + 1];

    const int tid = threadIdx.x;
    const int l   = tid & 63;
    const int w   = tid >> 6;       // wave 0..7 -> h-cols [32w, 32w+32)
    const int n   = l & 15;         // MFMA N slot
    const int rn  = n & 7;          // batch row
    const int hi  = n >> 3;         // rg-pair selector (dedup split)
    const int g   = l >> 4;
    const int r0  = blockIdx.x * BC;

    // ---- stage x (coalesced) ----
    for (int k = tid; k < BC * TDIM; k += 512) {
        int r = k >> 8, t = k & 255;
        x_lds[r][t] = x[(r0 + r) * TDIM + t];
    }

    // ---- W_h -> register fragments ----
    f16x8 wfrag[2][8];
    #pragma unroll
    for (int mt = 0; mt < 2; ++mt) {
        const int col = 32 * w + 16 * mt + n;
        #pragma unroll
        for (int kt = 0; kt < 8; ++kt) {
            #pragma unroll
            for (int e = 0; e < 8; ++e)
                wfrag[mt][kt][e] = (_Float16)Wh[(kt * 32 + g * 8 + e) * HDIM + col];
        }
    }

    // bh as vector inits (hcol = 32w+16mt+4g+rg)
    f32x4 bh0, bh1;
    #pragma unroll
    for (int rg = 0; rg < 4; ++rg) {
        bh0[rg] = bh[32 * w + 4 * g + rg];
        bh1[rg] = bh[32 * w + 16 + 4 * g + rg];
    }

    // ---- burst (inp-plane) assignment ----
    const int c_b  = tid >> 4;
    const int rn_b = (tid >> 1) & 7;
    const int hf_b = tid & 1;
    float Web[4], beb[4];
    #pragma unroll
    for (int r = 0; r < 4; ++r) {
        Web[r] = We[c_b * 8 + hf_b * 4 + r];
        beb[r] = be[c_b * 8 + hf_b * 4 + r];
    }
    const int bidx = c_b * 64 + rn_b * 8 + hf_b * 4;

    // ---- LDS addresses (chunk-major, conflict-free) ----
    const int base_r = g * 128 + rn * 16;              // bfrag: + kt*512
    int addr_w[2], iidx[2];
    #pragma unroll
    for (int mt = 0; mt < 2; ++mt) {
        addr_w[mt] = (4 * w + 2 * mt + (g >> 1)) * 128 + rn * 16 + (g & 1) * 8 + hi * 4;
        iidx[mt]   = (4 * w + 2 * mt + (g >> 1)) * 64 + rn * 8 + (g & 1) * 4 + hi * 2;
    }

    __syncthreads();

    // ---- prologue: inp planes tq = 0,1,2 ----
    #pragma unroll
    for (int tq = 0; tq < 3; ++tq) {
        const float xv = x_lds[rn_b][tq];
        f32x4 pk;
        #pragma unroll
        for (int r = 0; r < 4; ++r)
            pk[r] = fast_tanh(xv * Web[r] + beb[r]);
        *(f32x4*)&inp_lds[tq][bidx] = pk;
    }
    __syncthreads();

    // ---- v(0) = inp(0) (f32 -> f16) ----
    #pragma unroll
    for (int mt = 0; mt < 2; ++mt) {
        union { _Float16 h[2]; unsigned u; } pk;
        pk.h[0] = (_Float16)inp_lds[0][iidx[mt]];
        pk.h[1] = (_Float16)inp_lds[0][iidx[mt] + 1];
        *(unsigned*)(&vraw[0][0] + addr_w[mt]) = pk.u;
    }
    __syncthreads();

    int cur = 0;
    #pragma unroll 1
    for (int t = 0; t < TDIM - 1; ++t) {
        const char* vr = &vraw[cur][0];
        char*       vw = &vraw[cur ^ 1][0];
        const int   tq = t + 3;

        // -- reads first: bfrag burst + ip prefetch (latency off the tail) --
        f16x8 bfrag[8];
        #pragma unroll
        for (int kt = 0; kt < 8; ++kt)
            bfrag[kt] = *(const f16x8*)(vr + base_r + kt * 512);
        const float* ipl = &inp_lds[(t + 1) & 3][0];
        const float ip00 = ipl[iidx[0]], ip01 = ipl[iidx[0] + 1];
        const float ip10 = ipl[iidx[1]], ip11 = ipl[iidx[1] + 1];

        // -- MFMA clusters under raised priority (anti-phase vs partner wave) --
        f32x4 accE0 = bh0, accE1 = bh1;
        f32x4 accO0 = {0.f, 0.f, 0.f, 0.f}, accO1 = {0.f, 0.f, 0.f, 0.f};
        __builtin_amdgcn_s_setprio(1);
        #pragma unroll
        for (int kp = 0; kp < 4; ++kp) {
            accE0 = __builtin_amdgcn_mfma_f32_16x16x32_f16(wfrag[0][2 * kp],     bfrag[2 * kp],     accE0, 0, 0, 0);
            accO0 = __builtin_amdgcn_mfma_f32_16x16x32_f16(wfrag[0][2 * kp + 1], bfrag[2 * kp + 1], accO0, 0, 0, 0);
        }
        #pragma unroll
        for (int kp = 0; kp < 4; ++kp) {
            accE1 = __builtin_amdgcn_mfma_f32_16x16x32_f16(wfrag[1][2 * kp],     bfrag[2 * kp],     accE1, 0, 0, 0);
            accO1 = __builtin_amdgcn_mfma_f32_16x16x32_f16(wfrag[1][2 * kp + 1], bfrag[2 * kp + 1], accO1, 0, 0, 0);
        }
        __builtin_amdgcn_s_setprio(0);

        // -- shadow inp-tanh: independent VALU inside the MFMA latency window --
        if (tq < TDIM) {
            const float xv = x_lds[rn_b][tq];
            f32x4 pk;
            #pragma unroll
            for (int r = 0; r < 4; ++r)
                pk[r] = fast_tanh(xv * Web[r] + beb[r]);
            *(f32x4*)&inp_lds[tq & 3][bidx] = pk;
        }

        // -- tails (dedup'd: lane handles rg-pair {2hi, 2hi+1}) --
        {
            const float a0 = hi ? (accE0[2] + accO0[2]) : (accE0[0] + accO0[0]);
            const float a1 = hi ? (accE0[3] + accO0[3]) : (accE0[1] + accO0[1]);
            union { _Float16 h[2]; unsigned u; } pk;
            pk.h[0] = (_Float16)(fast_tanh(a0) + ip00);
            pk.h[1] = (_Float16)(fast_tanh(a1) + ip01);
            *(unsigned*)(vw + addr_w[0]) = pk.u;
        }
        {
            const float a0 = hi ? (accE1[2] + accO1[2]) : (accE1[0] + accO1[0]);
            const float a1 = hi ? (accE1[3] + accO1[3]) : (accE1[1] + accO1[1]);
            union { _Float16 h[2]; unsigned u; } pk;
            pk.h[0] = (_Float16)(fast_tanh(a0) + ip10);
            pk.h[1] = (_Float16)(fast_tanh(a1) + ip11);
            *(unsigned*)(vw + addr_w[1]) = pk.u;
        }
        cur ^= 1;
        __syncthreads();
    }

    // ---- peeled final step: h_fin = tanh(acc) ----
    {
        const char* vr = &vraw[cur][0];
        f16x8 bfrag[8];
        #pragma unroll
        for (int kt = 0; kt < 8; ++kt)
            bfrag[kt] = *(const f16x8*)(vr + base_r + kt * 512);

        f32x4 accE0 = bh0, accE1 = bh1;
        f32x4 accO0 = {0.f, 0.f, 0.f, 0.f}, accO1 = {0.f, 0.f, 0.f, 0.f};
        #pragma unroll
        for (int kp = 0; kp < 4; ++kp) {
            accE0 = __builtin_amdgcn_mfma_f32_16x16x32_f16(wfrag[0][2 * kp],     bfrag[2 * kp],     accE0, 0, 0, 0);
            accO0 = __builtin_amdgcn_mfma_f32_16x16x32_f16(wfrag[0][2 * kp + 1], bfrag[2 * kp + 1], accO0, 0, 0, 0);
        }
        #pragma unroll
        for (int kp = 0; kp < 4; ++kp) {
            accE1 = __builtin_amdgcn_mfma_f32_16x16x32_f16(wfrag[1][2 * kp],     bfrag[2 * kp],     accE1, 0, 0, 0);
            accO1 = __builtin_amdgcn_mfma_f32_16x16x32_f16(wfrag[1][2 * kp + 1], bfrag[2 * kp + 1], accO1, 0, 0, 0);
        }
        {
            const float a0 = hi ? (accE0[2] + accO0[2]) : (accE0[0] + accO0[0]);
            const float a1 = hi ? (accE0[3] + accO0[3]) : (accE0[1] + accO0[1]);
            const int hc = 32 * w + 4 * g + 2 * hi;
            h_fin[rn][hc + 0] = fast_tanh(a0);
            h_fin[rn][hc + 1] = fast_tanh(a1);
        }
        {
            const float a0 = hi ? (accE1[2] + accO1[2]) : (accE1[0] + accO1[0]);
            const float a1 = hi ? (accE1[3] + accO1[3]) : (accE1[1] + accO1[1]);
            const int hc = 32 * w + 16 + 4 * g + 2 * hi;
            h_fin[rn][hc + 0] = fast_tanh(a0);
            h_fin[rn][hc + 1] = fast_tanh(a1);
        }
    }
    __syncthreads();

    // ---- epilogue: out[r][v] = bo[v] + sum_i h[r][i] * Wo[i*V+v] ----
    if (tid < BC * VOUT) {
        const int r = tid / VOUT, vc = tid - r * VOUT;
        float sacc = bo[vc];
        #pragma unroll 8
        for (int i = 0; i < HDIM; ++i)
            sacc = fmaf(h_fin[r][i], Wo[i * VOUT + vc], sacc);
        out[(r0 + r) * VOUT + vc] = sacc;
    }
}

extern "C" void kernel_launch(void* const* d_in, const int* in_sizes, int n_in,
                              void* d_out, int out_size, void* d_ws, size_t ws_size,
                              hipStream_t stream) {
    const float* x  = (const float*)d_in[0];
    const float* We = (const float*)d_in[1];
    const float* be = (const float*)d_in[2];
    const float* Wh = (const float*)d_in[3];
    const float* bh = (const float*)d_in[4];
    const float* Wo = (const float*)d_in[5];
    const float* bo = (const float*)d_in[6];
    float* out = (float*)d_out;

    const int B = in_sizes[0] / TDIM;      // 2048
    const int nblocks = B / BC;            // 256

    rnn_fwd_v8<<<nblocks, 512, 0, stream>>>(x, We, be, Wh, bh, Wo, bo, out);
}

// Round 9
// 185.518 us; speedup vs baseline: 1.4197x; 1.0217x over previous
//
#include <hip/hip_runtime.h>

#define HDIM 256
#define TDIM 256
#define VOUT 10
#define BC   8     // batch rows per block -> 256 blocks, every CU busy

typedef _Float16 f16x8 __attribute__((ext_vector_type(8)));
typedef float    f32x4 __attribute__((ext_vector_type(4)));
typedef float    f32x2 __attribute__((ext_vector_type(2)));

__device__ __forceinline__ float fast_tanh(float a) {
    // tanh(a) = 1 - 2/(exp(2a)+1). |a| bounded (~32) -> no clamp needed.
    float e = __expf(2.0f * a);
    return 1.0f - 2.0f * __builtin_amdgcn_rcpf(e + 1.0f);
}

// v9 = v6 algorithm resliced to 16 waves/block (4 waves/SIMD) for latency
// hiding. Per-SIMD pipe totals unchanged (32 MFMA, same unique tanh, same
// LDS bytes); wave owns 16 h-cols (1 M-tile, wfrag = 32 VGPR). bh/zero fold
// into the first MFMA's C operand. No setprio (r8 FAILED), v6 ordering.
// Layouts (identical to v6): v chunk-major 16B (c=hcol>>3, rn); inp f32
// planes idx = c*64+rn*8+(hcol&7); both conflict-free (verified by phase).
__global__ __launch_bounds__(1024, 1) void rnn_fwd_v9(
    const float* __restrict__ x,    // [B, T]
    const float* __restrict__ We,   // [H]
    const float* __restrict__ be,   // [H]
    const float* __restrict__ Wh,   // [H, H] (in, out)
    const float* __restrict__ bh,   // [H]
    const float* __restrict__ Wo,   // [H, V]
    const float* __restrict__ bo,   // [V]
    float* __restrict__ out)        // [B, V]
{
    __shared__ __align__(16) char  vraw[2][BC * HDIM * 2];   // 2 x 4 KB f16
    __shared__ __align__(16) float inp_lds[4][BC * HDIM];    // 4 x 8 KB f32
    __shared__ float x_lds[BC][TDIM + 2];
    __shared__ float h_fin[BC][HDIM + 1];

    const int tid = threadIdx.x;
    const int l   = tid & 63;
    const int w   = tid >> 6;       // wave 0..15 -> h-cols [16w, 16w+16)
    const int n   = l & 15;         // MFMA N slot
    const int rn  = n & 7;          // batch row (n>=8 aliases)
    const int hi  = n >> 3;         // rg-pair selector (dedup split)
    const int g   = l >> 4;
    const int r0  = blockIdx.x * BC;

    // ---- stage x (coalesced, 2 per thread) ----
    for (int k = tid; k < BC * TDIM; k += 1024) {
        int r = k >> 8, t = k & 255;
        x_lds[r][t] = x[(r0 + r) * TDIM + t];
    }

    // ---- W_h -> register fragments (1 M-tile = 32 VGPR) ----
    // wfrag[kt][e] = Wh[(kt*32+g*8+e)*H + 16w+n]
    f16x8 wfrag[8];
    {
        const int col = 16 * w + n;
        #pragma unroll
        for (int kt = 0; kt < 8; ++kt) {
            #pragma unroll
            for (int e = 0; e < 8; ++e)
                wfrag[kt][e] = (_Float16)Wh[(kt * 32 + g * 8 + e) * HDIM + col];
        }
    }

    // bh vector: C-init of the even MFMA chain (hcol = 16w+4g+rg)
    f32x4 bhv;
    #pragma unroll
    for (int rg = 0; rg < 4; ++rg)
        bhv[rg] = bh[16 * w + 4 * g + rg];

    // ---- burst (inp-plane): thread owns plane f32 idx {2tid, 2tid+1} ----
    const int c_b  = tid >> 5;
    const int rem  = (2 * tid) & 63;
    const int rn_b = rem >> 3;
    const int o_b  = rem & 7;
    const float Web0 = We[c_b * 8 + o_b],     beb0 = be[c_b * 8 + o_b];
    const float Web1 = We[c_b * 8 + o_b + 1], beb1 = be[c_b * 8 + o_b + 1];
    const int bidx = 2 * tid;   // = c_b*64 + rn_b*8 + o_b  (chunk-major)

    // ---- LDS addresses ----
    const int base_r = g * 128 + rn * 16;          // bfrag: + kt*512
    const int c_own  = 2 * w + (g >> 1);           // chunk of owned hcol pair
    const int o_own  = (4 * g + 2 * hi) & 7;
    const int addr_w = c_own * 128 + rn * 16 + o_own * 2;   // f16 byte addr
    const int iidx   = c_own * 64 + rn * 8 + o_own;          // f32 idx

    __syncthreads();

    // ---- prologue: inp planes tq = 0,1,2 ----
    #pragma unroll
    for (int tq = 0; tq < 3; ++tq) {
        const float xv = x_lds[rn_b][tq];
        f32x2 pk;
        pk[0] = fast_tanh(xv * Web0 + beb0);
        pk[1] = fast_tanh(xv * Web1 + beb1);
        *(f32x2*)&inp_lds[tq][bidx] = pk;
    }
    __syncthreads();

    // ---- v(0) = inp(0) (f32 -> f16) ----
    {
        union { _Float16 h[2]; unsigned u; } pk;
        pk.h[0] = (_Float16)inp_lds[0][iidx];
        pk.h[1] = (_Float16)inp_lds[0][iidx + 1];
        *(unsigned*)(&vraw[0][0] + addr_w) = pk.u;
    }
    __syncthreads();

    int cur = 0;
    #pragma unroll 1
    for (int t = 0; t < TDIM - 1; ++t) {
        const char* vr = &vraw[cur][0];
        char*       vw = &vraw[cur ^ 1][0];
        const int   tq = t + 3;

        // reads first: bfrag burst + ip prefetch
        f16x8 bfrag[8];
        #pragma unroll
        for (int kt = 0; kt < 8; ++kt)
            bfrag[kt] = *(const f16x8*)(vr + base_r + kt * 512);
        const float* ipl = &inp_lds[(t + 1) & 3][0];
        const float ip0 = ipl[iidx], ip1 = ipl[iidx + 1];

        // shadow inp-tanh (unique work; fills lgkm/MFMA waits) -- v6 order
        if (tq < TDIM) {
            const float xv = x_lds[rn_b][tq];
            f32x2 pk;
            pk[0] = fast_tanh(xv * Web0 + beb0);
            pk[1] = fast_tanh(xv * Web1 + beb1);
            *(f32x2*)&inp_lds[tq & 3][bidx] = pk;
        }

        // 2 independent 4-deep MFMA chains; C-init folds bh / zero
        f32x4 accE = __builtin_amdgcn_mfma_f32_16x16x32_f16(wfrag[0], bfrag[0], bhv, 0, 0, 0);
        f32x4 zero = {0.f, 0.f, 0.f, 0.f};
        f32x4 accO = __builtin_amdgcn_mfma_f32_16x16x32_f16(wfrag[1], bfrag[1], zero, 0, 0, 0);
        #pragma unroll
        for (int kp = 1; kp < 4; ++kp) {
            accE = __builtin_amdgcn_mfma_f32_16x16x32_f16(wfrag[2 * kp],     bfrag[2 * kp],     accE, 0, 0, 0);
            accO = __builtin_amdgcn_mfma_f32_16x16x32_f16(wfrag[2 * kp + 1], bfrag[2 * kp + 1], accO, 0, 0, 0);
        }

        // dedup'd tail: lane handles rg-pair {2hi, 2hi+1}
        {
            const float a0 = hi ? (accE[2] + accO[2]) : (accE[0] + accO[0]);
            const float a1 = hi ? (accE[3] + accO[3]) : (accE[1] + accO[1]);
            union { _Float16 h[2]; unsigned u; } pk;
            pk.h[0] = (_Float16)(fast_tanh(a0) + ip0);
            pk.h[1] = (_Float16)(fast_tanh(a1) + ip1);
            *(unsigned*)(vw + addr_w) = pk.u;
        }
        cur ^= 1;
        __syncthreads();
    }

    // ---- peeled final step: h_fin = tanh(acc) ----
    {
        const char* vr = &vraw[cur][0];
        f16x8 bfrag[8];
        #pragma unroll
        for (int kt = 0; kt < 8; ++kt)
            bfrag[kt] = *(const f16x8*)(vr + base_r + kt * 512);

        f32x4 accE = __builtin_amdgcn_mfma_f32_16x16x32_f16(wfrag[0], bfrag[0], bhv, 0, 0, 0);
        f32x4 zero = {0.f, 0.f, 0.f, 0.f};
        f32x4 accO = __builtin_amdgcn_mfma_f32_16x16x32_f16(wfrag[1], bfrag[1], zero, 0, 0, 0);
        #pragma unroll
        for (int kp = 1; kp < 4; ++kp) {
            accE = __builtin_amdgcn_mfma_f32_16x16x32_f16(wfrag[2 * kp],     bfrag[2 * kp],     accE, 0, 0, 0);
            accO = __builtin_amdgcn_mfma_f32_16x16x32_f16(wfrag[2 * kp + 1], bfrag[2 * kp + 1], accO, 0, 0, 0);
        }
        const float a0 = hi ? (accE[2] + accO[2]) : (accE[0] + accO[0]);
        const float a1 = hi ? (accE[3] + accO[3]) : (accE[1] + accO[1]);
        const int hc = 16 * w + 4 * g + 2 * hi;
        h_fin[rn][hc + 0] = fast_tanh(a0);
        h_fin[rn][hc + 1] = fast_tanh(a1);
    }
    __syncthreads();

    // ---- epilogue: out[r][v] = bo[v] + sum_i h[r][i] * Wo[i*V+v] ----
    if (tid < BC * VOUT) {
        const int r = tid / VOUT, vc = tid - r * VOUT;
        float sacc = bo[vc];
        #pragma unroll 8
        for (int i = 0; i < HDIM; ++i)
            sacc = fmaf(h_fin[r][i], Wo[i * VOUT + vc], sacc);
        out[(r0 + r) * VOUT + vc] = sacc;
    }
}

extern "C" void kernel_launch(void* const* d_in, const int* in_sizes, int n_in,
                              void* d_out, int out_size, void* d_ws, size_t ws_size,
                              hipStream_t stream) {
    const float* x  = (const float*)d_in[0];
    const float* We = (const float*)d_in[1];
    const float* be = (const float*)d_in[2];
    const float* Wh = (const float*)d_in[3];
    const float* bh = (const float*)d_in[4];
    const float* Wo = (const float*)d_in[5];
    const float* bo = (const float*)d_in[6];
    float* out = (float*)d_out;

    const int B = in_sizes[0] / TDIM;      // 2048
    const int nblocks = B / BC;            // 256

    rnn_fwd_v9<<<nblocks, 1024, 0, stream>>>(x, We, be, Wh, bh, Wo, bo, out);
}

// Round 10
// 155.411 us; speedup vs baseline: 1.6947x; 1.1937x over previous
//
#include <hip/hip_runtime.h>

#define HDIM 256
#define TDIM 256
#define VOUT 10
#define BC   8     // batch rows per block -> 256 blocks, every CU busy

typedef _Float16 f16x8 __attribute__((ext_vector_type(8)));
typedef float    f32x4 __attribute__((ext_vector_type(4)));

__device__ __forceinline__ float fast_tanh(float a) {
    // tanh(a) = 1 - 2/(exp(2a)+1). |a| bounded (~32) -> no clamp needed.
    float e = __expf(2.0f * a);
    return 1.0f - 2.0f * __builtin_amdgcn_rcpf(e + 1.0f);
}

// v10 = v6 structure (BC=8, 8 waves, 2x N-alias, dedup'd tanh, conflict-free
// chunk-major LDS) minus the inp-plane machinery: each thread computes its
// own 4 inp-tanh directly from x_lds (same tanh count, bitwise-same math,
// -32KB LDS, fewer LDS ops). bh folded into first MFMA C; last step peeled;
// x-read issued before bfrag burst (in-order lgkm -> x ready first).
__global__ __launch_bounds__(512, 1) void rnn_fwd_v10(
    const float* __restrict__ x,    // [B, T]
    const float* __restrict__ We,   // [H]
    const float* __restrict__ be,   // [H]
    const float* __restrict__ Wh,   // [H, H] (in, out)
    const float* __restrict__ bh,   // [H]
    const float* __restrict__ Wo,   // [H, V]
    const float* __restrict__ bo,   // [V]
    float* __restrict__ out)        // [B, V]
{
    __shared__ __align__(16) char vraw[2][BC * HDIM * 2];   // 2 x 4 KB f16
    __shared__ float x_lds[BC][TDIM + 2];                   // 8.3 KB
    __shared__ float h_fin[BC][HDIM + 1];                   // 8.2 KB

    const int tid = threadIdx.x;
    const int l   = tid & 63;
    const int w   = tid >> 6;       // wave 0..7 -> h-cols [32w, 32w+32)
    const int n   = l & 15;         // MFMA N slot
    const int rn  = n & 7;          // batch row (n>=8 aliases)
    const int hi  = n >> 3;         // rg-pair selector (dedup split)
    const int g   = l >> 4;
    const int r0  = blockIdx.x * BC;

    // ---- stage x (coalesced) ----
    for (int k = tid; k < BC * TDIM; k += 512) {
        int r = k >> 8, t = k & 255;
        x_lds[r][t] = x[(r0 + r) * TDIM + t];
    }

    // ---- W_h -> register fragments ----
    // wfrag[mt][kt][e] = Wh[(kt*32+g*8+e)*H + 32w+16mt+n]
    f16x8 wfrag[2][8];
    #pragma unroll
    for (int mt = 0; mt < 2; ++mt) {
        const int col = 32 * w + 16 * mt + n;
        #pragma unroll
        for (int kt = 0; kt < 8; ++kt) {
            #pragma unroll
            for (int e = 0; e < 8; ++e)
                wfrag[mt][kt][e] = (_Float16)Wh[(kt * 32 + g * 8 + e) * HDIM + col];
        }
    }

    // bh as C-init vectors (hcol = 32w+16mt+4g+rg)
    f32x4 bh0, bh1;
    #pragma unroll
    for (int rg = 0; rg < 4; ++rg) {
        bh0[rg] = bh[32 * w + 4 * g + rg];
        bh1[rg] = bh[32 * w + 16 + 4 * g + rg];
    }

    // ---- own-hcol We/be (for direct inp-tanh): hcols 32w+16mt+4g+2hi+{0,1} ----
    float WeO[2][2], beO[2][2];
    #pragma unroll
    for (int mt = 0; mt < 2; ++mt) {
        const int hc = 32 * w + 16 * mt + 4 * g + 2 * hi;
        WeO[mt][0] = We[hc];     beO[mt][0] = be[hc];
        WeO[mt][1] = We[hc + 1]; beO[mt][1] = be[hc + 1];
    }

    // ---- LDS addresses (chunk-major, conflict-free) ----
    const int base_r = g * 128 + rn * 16;              // bfrag: + kt*512
    int addr_w[2];
    #pragma unroll
    for (int mt = 0; mt < 2; ++mt)
        addr_w[mt] = (4 * w + 2 * mt + (g >> 1)) * 128 + rn * 16 + (g & 1) * 8 + hi * 4;

    __syncthreads();

    // ---- v(0) = tanh(x[:,0]*We + be)  (h0 = 0) ----
    {
        const float xv = x_lds[rn][0];
        #pragma unroll
        for (int mt = 0; mt < 2; ++mt) {
            union { _Float16 h[2]; unsigned u; } pk;
            pk.h[0] = (_Float16)fast_tanh(xv * WeO[mt][0] + beO[mt][0]);
            pk.h[1] = (_Float16)fast_tanh(xv * WeO[mt][1] + beO[mt][1]);
            *(unsigned*)(&vraw[0][0] + addr_w[mt]) = pk.u;
        }
    }
    __syncthreads();

    int cur = 0;
    #pragma unroll 1
    for (int t = 0; t < TDIM - 1; ++t) {
        const char* vr = &vraw[cur][0];
        char*       vw = &vraw[cur ^ 1][0];

        // x first (in-order lgkm: ready before bfrag drain), then bfrag burst
        const float xv = x_lds[rn][t + 1];
        f16x8 bfrag[8];
        #pragma unroll
        for (int kt = 0; kt < 8; ++kt)
            bfrag[kt] = *(const f16x8*)(vr + base_r + kt * 512);

        // direct inp-tanh for own hcols (overlaps bfrag wait / MFMA)
        float ip[2][2];
        #pragma unroll
        for (int mt = 0; mt < 2; ++mt) {
            ip[mt][0] = fast_tanh(xv * WeO[mt][0] + beO[mt][0]);
            ip[mt][1] = fast_tanh(xv * WeO[mt][1] + beO[mt][1]);
        }

        // 4 independent 4-deep MFMA chains; bh/zero folded into first C
        const f32x4 zero = {0.f, 0.f, 0.f, 0.f};
        f32x4 accE0 = __builtin_amdgcn_mfma_f32_16x16x32_f16(wfrag[0][0], bfrag[0], bh0,  0, 0, 0);
        f32x4 accE1 = __builtin_amdgcn_mfma_f32_16x16x32_f16(wfrag[1][0], bfrag[0], bh1,  0, 0, 0);
        f32x4 accO0 = __builtin_amdgcn_mfma_f32_16x16x32_f16(wfrag[0][1], bfrag[1], zero, 0, 0, 0);
        f32x4 accO1 = __builtin_amdgcn_mfma_f32_16x16x32_f16(wfrag[1][1], bfrag[1], zero, 0, 0, 0);
        #pragma unroll
        for (int kp = 1; kp < 4; ++kp) {
            accE0 = __builtin_amdgcn_mfma_f32_16x16x32_f16(wfrag[0][2 * kp],     bfrag[2 * kp],     accE0, 0, 0, 0);
            accE1 = __builtin_amdgcn_mfma_f32_16x16x32_f16(wfrag[1][2 * kp],     bfrag[2 * kp],     accE1, 0, 0, 0);
            accO0 = __builtin_amdgcn_mfma_f32_16x16x32_f16(wfrag[0][2 * kp + 1], bfrag[2 * kp + 1], accO0, 0, 0, 0);
            accO1 = __builtin_amdgcn_mfma_f32_16x16x32_f16(wfrag[1][2 * kp + 1], bfrag[2 * kp + 1], accO1, 0, 0, 0);
        }

        // dedup'd tails: lane handles rg-pair {2hi, 2hi+1}
        {
            const float a0 = hi ? (accE0[2] + accO0[2]) : (accE0[0] + accO0[0]);
            const float a1 = hi ? (accE0[3] + accO0[3]) : (accE0[1] + accO0[1]);
            union { _Float16 h[2]; unsigned u; } pk;
            pk.h[0] = (_Float16)(fast_tanh(a0) + ip[0][0]);
            pk.h[1] = (_Float16)(fast_tanh(a1) + ip[0][1]);
            *(unsigned*)(vw + addr_w[0]) = pk.u;
        }
        {
            const float a0 = hi ? (accE1[2] + accO1[2]) : (accE1[0] + accO1[0]);
            const float a1 = hi ? (accE1[3] + accO1[3]) : (accE1[1] + accO1[1]);
            union { _Float16 h[2]; unsigned u; } pk;
            pk.h[0] = (_Float16)(fast_tanh(a0) + ip[1][0]);
            pk.h[1] = (_Float16)(fast_tanh(a1) + ip[1][1]);
            *(unsigned*)(vw + addr_w[1]) = pk.u;
        }
        cur ^= 1;
        __syncthreads();
    }

    // ---- peeled final step: h_fin = tanh(acc) ----
    {
        const char* vr = &vraw[cur][0];
        f16x8 bfrag[8];
        #pragma unroll
        for (int kt = 0; kt < 8; ++kt)
            bfrag[kt] = *(const f16x8*)(vr + base_r + kt * 512);

        const f32x4 zero = {0.f, 0.f, 0.f, 0.f};
        f32x4 accE0 = __builtin_amdgcn_mfma_f32_16x16x32_f16(wfrag[0][0], bfrag[0], bh0,  0, 0, 0);
        f32x4 accE1 = __builtin_amdgcn_mfma_f32_16x16x32_f16(wfrag[1][0], bfrag[0], bh1,  0, 0, 0);
        f32x4 accO0 = __builtin_amdgcn_mfma_f32_16x16x32_f16(wfrag[0][1], bfrag[1], zero, 0, 0, 0);
        f32x4 accO1 = __builtin_amdgcn_mfma_f32_16x16x32_f16(wfrag[1][1], bfrag[1], zero, 0, 0, 0);
        #pragma unroll
        for (int kp = 1; kp < 4; ++kp) {
            accE0 = __builtin_amdgcn_mfma_f32_16x16x32_f16(wfrag[0][2 * kp],     bfrag[2 * kp],     accE0, 0, 0, 0);
            accE1 = __builtin_amdgcn_mfma_f32_16x16x32_f16(wfrag[1][2 * kp],     bfrag[2 * kp],     accE1, 0, 0, 0);
            accO0 = __builtin_amdgcn_mfma_f32_16x16x32_f16(wfrag[0][2 * kp + 1], bfrag[2 * kp + 1], accO0, 0, 0, 0);
            accO1 = __builtin_amdgcn_mfma_f32_16x16x32_f16(wfrag[1][2 * kp + 1], bfrag[2 * kp + 1], accO1, 0, 0, 0);
        }
        {
            const float a0 = hi ? (accE0[2] + accO0[2]) : (accE0[0] + accO0[0]);
            const float a1 = hi ? (accE0[3] + accO0[3]) : (accE0[1] + accO0[1]);
            const int hc = 32 * w + 4 * g + 2 * hi;
            h_fin[rn][hc + 0] = fast_tanh(a0);
            h_fin[rn][hc + 1] = fast_tanh(a1);
        }
        {
            const float a0 = hi ? (accE1[2] + accO1[2]) : (accE1[0] + accO1[0]);
            const float a1 = hi ? (accE1[3] + accO1[3]) : (accE1[1] + accO1[1]);
            const int hc = 32 * w + 16 + 4 * g + 2 * hi;
            h_fin[rn][hc + 0] = fast_tanh(a0);
            h_fin[rn][hc + 1] = fast_tanh(a1);
        }
    }
    __syncthreads();

    // ---- epilogue: out[r][v] = bo[v] + sum_i h[r][i] * Wo[i*V+v] ----
    if (tid < BC * VOUT) {
        const int r = tid / VOUT, vc = tid - r * VOUT;
        float sacc = bo[vc];
        #pragma unroll 8
        for (int i = 0; i < HDIM; ++i)
            sacc = fmaf(h_fin[r][i], Wo[i * VOUT + vc], sacc);
        out[(r0 + r) * VOUT + vc] = sacc;
    }
}

extern "C" void kernel_launch(void* const* d_in, const int* in_sizes, int n_in,
                              void* d_out, int out_size, void* d_ws, size_t ws_size,
                              hipStream_t stream) {
    const float* x  = (const float*)d_in[0];
    const float* We = (const float*)d_in[1];
    const float* be = (const float*)d_in[2];
    const float* Wh = (const float*)d_in[3];
    const float* bh = (const float*)d_in[4];
    const float* Wo = (const float*)d_in[5];
    const float* bo = (const float*)d_in[6];
    float* out = (float*)d_out;

    const int B = in_sizes[0] / TDIM;      // 2048
    const int nblocks = B / BC;            // 256

    rnn_fwd_v10<<<nblocks, 512, 0, stream>>>(x, We, be, Wh, bh, Wo, bo, out);
}